// Round 15
// baseline (2038.428 us; speedup 1.0000x reference)
//
#include <hip/hip_runtime.h>
#include <hip/hip_bf16.h>
#include <stdint.h>
#include <math.h>

#define DEVINL static __device__ __forceinline__

static constexpr int BB = 8, NN = 4096, SS = 1024, KK = 24, CC = 64;
static constexpr int INCH = 131, OUTCH = 128;

typedef __attribute__((ext_vector_type(8))) short short8v;  // 8 bf16 (4 VGPR)
typedef __attribute__((ext_vector_type(4))) float f32x4;
typedef __attribute__((ext_vector_type(2))) float f32x2;

#define MFMA16(a, b, c) __builtin_amdgcn_mfma_f32_16x16x32_bf16(a, b, c, 0, 0, 0)

// Truncation-based compensated bf16 split: hi = trunc(v); lo compensates
// exactly (v - trunc(v) is exact in f32).
DEVINL unsigned short bfhi(float v) {
  return (unsigned short)(__float_as_uint(v) >> 16);
}
DEVINL float bfhif(float v) {
  return __uint_as_float(__float_as_uint(v) & 0xFFFF0000u);
}
DEVINL unsigned short bflo(float v) {
  float r = __fsub_rn(v, bfhif(v));
  return (unsigned short)(__float_as_uint(r) >> 16);
}

// ---------------------------------------------------------------------------
// prep 1: xyz -> SoA f32 + per-point ||p||^2 (exact np op order, no FMA fusion)
// ---------------------------------------------------------------------------
__global__ __launch_bounds__(256) void k_prep_xyz(
    const float* __restrict__ xyz,
    float* __restrict__ xs, float* __restrict__ ys,
    float* __restrict__ zs, float* __restrict__ sb) {
  int e = blockIdx.x * 256 + threadIdx.x;
  if (e >= BB * NN) return;
  float x = xyz[e * 3 + 0];
  float y = xyz[e * 3 + 1];
  float z = xyz[e * 3 + 2];
  xs[e] = x; ys[e] = y; zs[e] = z;
  sb[e] = __fadd_rn(__fadd_rn(__fmul_rn(x, x), __fmul_rn(y, y)), __fmul_rn(z, z));
}

// ---------------------------------------------------------------------------
// prep 2: (a) wt_sq transpose for k_pos, (b) folded BN scale/bias, (c) MFMA
// weight fragments for k_pre layers 0..4 in split-bf16 (trunc hi / comp lo).
// ---------------------------------------------------------------------------
__global__ __launch_bounds__(256) void k_prep_w(
    const float* __restrict__ tw,
    const float* __restrict__ pw1, const float* __restrict__ pw2,
    const float* __restrict__ qw1, const float* __restrict__ qw2,
    const float* __restrict__ tb,  const float* __restrict__ tbn,
    const float* __restrict__ pb1, const float* __restrict__ pbn1,
    const float* __restrict__ pb2, const float* __restrict__ pbn2,
    const float* __restrict__ qb1, const float* __restrict__ qbn1,
    const float* __restrict__ qb2, const float* __restrict__ qbn2,
    float* __restrict__ wt_sq, float* __restrict__ bnsb,
    unsigned short* __restrict__ wfhi, unsigned short* __restrict__ wflo) {
  int e = blockIdx.x * 256 + threadIdx.x;
  const int NSQ = 8 * 128 * 128;  // 131072 (k_pos still uses layers 4..7)
  const int NBN = 9 * 128;
  const int NFR = 168 * 64;       // fragment fill threads
  if (e < NSQ) {
    int layer = e >> 14, m = e & 16383;
    int ci = m >> 7, co = m & 127;
    const float* src;
    switch (layer) {
      case 0: src = pw1;         break;
      case 1: src = pw2;         break;
      case 2: src = pw1 + 16384; break;
      case 3: src = pw2 + 16384; break;
      case 4: src = qw1;         break;
      case 5: src = qw2;         break;
      case 6: src = qw1 + 16384; break;
      default: src = qw2 + 16384; break;
    }
    wt_sq[layer * 16384 + ci * 128 + co] = src[co * 128 + ci];
  } else if (e < NSQ + NBN) {
    int r = e - NSQ;
    int L = r >> 7, co = r & 127;
    const float *bn, *bc;
    switch (L) {
      case 0: bn = tbn;        bc = tb;        break;
      case 1: bn = pbn1;       bc = pb1;       break;
      case 2: bn = pbn2;       bc = pb2;       break;
      case 3: bn = pbn1 + 512; bc = pb1 + 128; break;
      case 4: bn = pbn2 + 512; bc = pb2 + 128; break;
      case 5: bn = qbn1;       bc = qb1;       break;
      case 6: bn = qbn2;       bc = qb2;       break;
      case 7: bn = qbn1 + 512; bc = qb1 + 128; break;
      default: bn = qbn2 + 512; bc = qb2 + 128; break;
    }
    float g  = bn[co];
    float be = bn[128 + co];
    float mu = bn[256 + co];
    float va = bn[384 + co];
    float bcv = bc[co];
    float sc = g / sqrtf(va + 1e-5f);
    float bi = (bcv - mu) * sc + be;
    bnsb[L * 256 + co] = sc;
    bnsb[L * 256 + 128 + co] = bi;
  } else if (e < NSQ + NBN + NFR) {
    int r = e - (NSQ + NBN);
    int T = r >> 6, lane = r & 63;
    int L, ks, mt;
    if (T < 40) { L = 0; ks = T >> 3; mt = T & 7; }
    else { int r2 = T - 40; L = 1 + (r2 >> 5); int r3 = r2 & 31; ks = r3 >> 3; mt = r3 & 7; }
    const float* src;
    int K, stride;
    switch (L) {
      case 0:  src = tw;          K = 131; stride = 131; break;
      case 1:  src = pw1;         K = 128; stride = 128; break;
      case 2:  src = pw2;         K = 128; stride = 128; break;
      case 3:  src = pw1 + 16384; K = 128; stride = 128; break;
      default: src = pw2 + 16384; K = 128; stride = 128; break;
    }
    int m = lane & 15, kb = lane >> 4;
    int co = mt * 16 + m;
    int base = (T * 64 + lane) * 8;
#pragma unroll
    for (int j = 0; j < 8; j++) {
      int ci = ks * 32 + kb * 8 + j;
      float w = (ci < K) ? src[co * stride + ci] : 0.f;
      wfhi[base + j] = bfhi(w);
      wflo[base + j] = bflo(w);
    }
  }
}

// ---------------------------------------------------------------------------
// DPP wave max (ALU-only). row_shr:1/2/4/8 + row_bcast:15/31 leave the
// full-wave result in lane 63. Invalid lanes read `old` = identity (-inf).
// ---------------------------------------------------------------------------
DEVINL float wave_max_f32_l63(float x) {
#define STEPF(C)                                                                \
  {                                                                             \
    int o = __builtin_amdgcn_update_dpp(0xff800000, __float_as_int(x), C, 0xf, 0xf, false); \
    x = fmaxf(x, __int_as_float(o));                                            \
  }
  STEPF(0x111) STEPF(0x112) STEPF(0x114) STEPF(0x118) STEPF(0x142) STEPF(0x143)
#undef STEPF
  return x;
}

// ---------------------------------------------------------------------------
// FPS v9 (barrier-free): ONE wave per batch; 64 contiguous points/thread as
// 32 packed f32x2 pairs in registers (~290 VGPR, no spill at 1 wave/SIMD).
// Per iter: packed update + inline (val,n) select (first-n on tie), DPP
// f32-max -> readlane(63) -> ballot -> ffs (lowest lane = min n since lanes
// own ascending ranges) -> readlane(bestn) -> broadcast LDS coord read.
// NO __syncthreads, NO cross-wave key exchange, NO block tree.
// ---------------------------------------------------------------------------
__global__ __launch_bounds__(64, 1) void k_fps(
    const float* __restrict__ xs, const float* __restrict__ ys,
    const float* __restrict__ zs, const float* __restrict__ sb,
    const float* __restrict__ points,
    float* __restrict__ nxyz, float* __restrict__ sa, float* __restrict__ newp) {
  __shared__ float lxl[NN], lyl[NN], lzl[NN];
  __shared__ int fpsl[SS];
  const int b = blockIdx.x, t = threadIdx.x;  // t == lane
  const float* bx = xs + b * NN;
  const float* by = ys + b * NN;
  const float* bz = zs + b * NN;
  f32x2 rx[32], ry[32], rz[32], d[32];
  const int n0 = t * 64;
#pragma unroll
  for (int j = 0; j < 32; j++) {
    int n = n0 + 2 * j;
    rx[j].x = bx[n]; rx[j].y = bx[n + 1];
    ry[j].x = by[n]; ry[j].y = by[n + 1];
    rz[j].x = bz[n]; rz[j].y = bz[n + 1];
    lxl[n] = rx[j].x; lxl[n + 1] = rx[j].y;
    lyl[n] = ry[j].x; lyl[n + 1] = ry[j].y;
    lzl[n] = rz[j].x; lzl[n + 1] = rz[j].y;
    d[j].x = 1e10f; d[j].y = 1e10f;
  }
  __syncthreads();
  float px = lxl[0], py = lyl[0], pz = lzl[0];
  if (t == 0) fpsl[0] = 0;
#pragma unroll 1
  for (int i = 1; i < SS; i++) {
    float bestval = -1.f;
    int bestn = 0;
    f32x2 px2, py2, pz2;
    px2.x = px; px2.y = px;
    py2.x = py; py2.y = py;
    pz2.x = pz; pz2.y = pz;
#pragma unroll
    for (int j = 0; j < 32; j++) {
      f32x2 dd;
      {
#pragma clang fp contract(off)
        f32x2 dx = rx[j] - px2;
        f32x2 dy = ry[j] - py2;
        f32x2 dz = rz[j] - pz2;
        dd = (dx * dx + dy * dy) + dz * dz;
      }
      float nd0 = fminf(d[j].x, dd.x);
      float nd1 = fminf(d[j].y, dd.y);
      d[j].x = nd0; d[j].y = nd1;
      if (nd0 > bestval) { bestval = nd0; bestn = n0 + 2 * j; }      // first-n
      if (nd1 > bestval) { bestval = nd1; bestn = n0 + 2 * j + 1; }  // on tie
    }
    float wmax = __int_as_float(
        __builtin_amdgcn_readlane(__float_as_int(wave_max_f32_l63(bestval)), 63));
    unsigned long long el = __ballot(bestval == wmax);
    int fl = (int)__ffsll(el) - 1;            // lowest eligible lane = min n
    int n = __builtin_amdgcn_readlane(bestn, fl);
    px = lxl[n]; py = lyl[n]; pz = lzl[n];
    if (t == 0) fpsl[i] = n;
  }
  __syncthreads();
  for (int s = t; s < SS; s += 64) {
    int row = fpsl[s];
    nxyz[(b * SS + s) * 3 + 0] = lxl[row];
    nxyz[(b * SS + s) * 3 + 1] = lyl[row];
    nxyz[(b * SS + s) * 3 + 2] = lzl[row];
    sa[b * SS + s] = sb[b * NN + row];
  }
  for (int e = t; e < SS * CC; e += 64) {
    int s = e >> 6, c = e & 63;
    int row = fpsl[s];
    newp[(b * SS + s) * CC + c] = points[(b * NN + row) * CC + c];
  }
}

// ---------------------------------------------------------------------------
// KNN + std partial sums (revert to the u64-shuffle version from the best
// measured 1036us config).
// ---------------------------------------------------------------------------
__global__ __launch_bounds__(256, 2) void k_knn(
    const float* __restrict__ xs, const float* __restrict__ ys,
    const float* __restrict__ zs,
    const float* __restrict__ nxyz, const float* __restrict__ sa,
    const float* __restrict__ points, const float* __restrict__ newp,
    int* __restrict__ knn, double* __restrict__ spart) {
  __shared__ float lx[NN], ly[NN], lz[NN];
  __shared__ int selk[4][KK];
  const int blk = blockIdx.x, t = threadIdx.x, wid = t >> 6, lane = t & 63;
  const int b = blk >> 8;
  for (int e = t; e < NN; e += 256) {
    lx[e] = xs[b * NN + e]; ly[e] = ys[b * NN + e]; lz[e] = zs[b * NN + e];
  }
  __syncthreads();
  const int q = blk * 4 + wid;
  float qx = nxyz[q * 3 + 0], qy = nxyz[q * 3 + 1], qz = nxyz[q * 3 + 2];
  float qa = sa[q];
  unsigned keys[64];
#pragma unroll
  for (int j = 0; j < 64; j++) {
    int n = j * 64 + lane;
    float x = lx[n], y = ly[n], z = lz[n];
    float sbn = __fadd_rn(__fadd_rn(__fmul_rn(x, x), __fmul_rn(y, y)), __fmul_rn(z, z));
    float dot = __fadd_rn(__fadd_rn(__fmul_rn(qx, x), __fmul_rn(qy, y)), __fmul_rn(qz, z));
    float dd = __fsub_rn(__fadd_rn(qa, sbn), __fmul_rn(2.0f, dot));
    unsigned u = __float_as_uint(dd);
    u ^= (0x80000000u | (unsigned)((int)u >> 31));
    keys[j] = u;
  }
#pragma unroll 1
  for (int r = 0; r < KK; r++) {
    unsigned bv = keys[0];
    int bj = 0;
#pragma unroll
    for (int j = 1; j < 64; j++) {
      if (keys[j] < bv) { bv = keys[j]; bj = j; }
    }
    unsigned long long gk = ((unsigned long long)bv << 32) | (unsigned)(bj * 64 + lane);
#pragma unroll
    for (int m = 1; m < 64; m <<= 1) {
      unsigned long long o = __shfl_xor(gk, m);
      gk = o < gk ? o : gk;
    }
    int n = (int)(unsigned)gk;
    if (lane == 0) { knn[q * KK + r] = n; selk[wid][r] = n; }
    if (lane == (n & 63)) {
      int jj = n >> 6;
#pragma unroll
      for (int j = 0; j < 64; j++)
        if (j == jj) keys[j] = 0xFFFFFFFFu;
    }
  }
  double s1 = 0.0, s2 = 0.0;
#pragma unroll 1
  for (int i = 0; i < 26; i++) {
    int e = lane + 64 * i;
    if (e < KK * 67) {
      int k = e / 67, c = e - k * 67;
      int n = selk[wid][k];
      float g, mm;
      if (c < CC) {
        g = points[(b * NN + n) * CC + c];
        mm = newp[q * CC + c];
      } else {
        int cc = c - CC;
        g = cc == 0 ? lx[n] : (cc == 1 ? ly[n] : lz[n]);
        mm = nxyz[q * 3 + cc];
      }
      float v = __fsub_rn(g, mm);
      s1 += (double)v;
      s2 += (double)v * (double)v;
    }
  }
#pragma unroll
  for (int m = 1; m < 64; m <<= 1) {
    s1 += __shfl_xor(s1, m);
    s2 += __shfl_xor(s2, m);
  }
  if (lane == 0) { spart[q * 2 + 0] = s1; spart[q * 2 + 1] = s2; }
}

// ---------------------------------------------------------------------------
// finalize std per batch -> stdp = std + 1e-5 (unchanged)
// ---------------------------------------------------------------------------
__global__ __launch_bounds__(256) void k_stdfin(
    const double* __restrict__ spart, float* __restrict__ stdp) {
  __shared__ double a1[256], a2[256];
  const int b = blockIdx.x, t = threadIdx.x;
  double s1 = 0.0, s2 = 0.0;
  for (int i = t; i < SS; i += 256) {
    s1 += spart[(b * SS + i) * 2 + 0];
    s2 += spart[(b * SS + i) * 2 + 1];
  }
  a1[t] = s1; a2[t] = s2;
  __syncthreads();
  for (int w = 128; w > 0; w >>= 1) {
    if (t < w) { a1[t] += a1[t + w]; a2[t] += a2[t + w]; }
    __syncthreads();
  }
  if (t == 0) {
    const double n = (double)SS * KK * 67;
    double m = a1[0] / n;
    double var = (a2[0] - a1[0] * m) / (n - 1.0);
    if (var < 0.0) var = 0.0;
    float stdf = (float)sqrt(var);
    stdp[b] = stdf + 1e-5f;
  }
}

// ---------------------------------------------------------------------------
// fused PreExtraction v5 (round-11 version, LB(256,4)) -- unchanged
// ---------------------------------------------------------------------------
static constexpr int BST = 168;  // acts row stride (bf16 elems)
static constexpr int XST = 132;  // residual row stride (f32)

__global__ __launch_bounds__(256, 4) void k_pre(
    const float* __restrict__ points,
    const float* __restrict__ alpha, const float* __restrict__ beta,
    const float* __restrict__ xs, const float* __restrict__ ys, const float* __restrict__ zs,
    const float* __restrict__ nxyz, const float* __restrict__ newp,
    const float* __restrict__ stdp, const int* __restrict__ knn,
    const unsigned short* __restrict__ wfhi, const unsigned short* __restrict__ wflo,
    const float* __restrict__ bnsb, float* __restrict__ pre_out) {
  __shared__ unsigned short Bhi[32 * BST];
  __shared__ unsigned short Blo[32 * BST];
  __shared__ float Xres[32 * XST];
  __shared__ int kn[KK];
  __shared__ float npl[CC], nxl[3], al[67], bt[67];
  __shared__ float stds;
  const int q = blockIdx.x, b = q >> 10, t = threadIdx.x;
  for (int e = t; e < 32 * BST; e += 256) { Bhi[e] = 0; Blo[e] = 0; }
  if (t < KK) kn[t] = knn[q * KK + t];
  if (t < 67) { al[t] = alpha[t]; bt[t] = beta[t]; }
  if (t < CC) npl[t] = newp[q * CC + t];
  if (t < 3) nxl[t] = nxyz[q * 3 + t];
  if (t == 0) stds = stdp[b];
  __syncthreads();
  for (int e = t; e < KK * 67; e += 256) {
    int k = e / 67, c = e - k * 67;
    int n = kn[k];
    float g, mm;
    if (c < CC) {
      g = points[(b * NN + n) * CC + c];
      mm = npl[c];
    } else {
      int cc = c - CC;
      g = cc == 0 ? xs[b * NN + n] : (cc == 1 ? ys[b * NN + n] : zs[b * NN + n]);
      mm = nxl[cc];
    }
    float v = __fsub_rn(g, mm);
    float tt = __fdiv_rn(v, stds);
    float val = __fadd_rn(__fmul_rn(al[c], tt), bt[c]);
    Bhi[k * BST + c] = bfhi(val);
    Blo[k * BST + c] = bflo(val);
  }
  for (int e = t; e < CC * KK; e += 256) {
    int c = e / KK, k = e - c * KK;
    float val = npl[c];
    Bhi[k * BST + 67 + c] = bfhi(val);
    Blo[k * BST + 67 + c] = bflo(val);
  }
  __syncthreads();

  const int wv = t >> 6, lane = t & 63;
  const int g4 = lane >> 4;
  const int l15 = lane & 15;
  const int mt0 = wv * 2;

#pragma unroll
  for (int L = 0; L < 5; ++L) {
    const int nks = (L == 0) ? 5 : 4;
    const int wtb = (L == 0) ? 0 : (8 + 32 * L);
    const bool addres = (L == 2) || (L == 4);
    const bool wres = (L == 0) || (L == 2);
    const bool pool = (L == 4);
    f32x4 acc00 = {0.f, 0.f, 0.f, 0.f}, acc01 = {0.f, 0.f, 0.f, 0.f};
    f32x4 acc10 = {0.f, 0.f, 0.f, 0.f}, acc11 = {0.f, 0.f, 0.f, 0.f};
#pragma unroll
    for (int ks = 0; ks < nks; ++ks) {
      const int tb = (wtb + ks * 8 + mt0) * 64 + lane;
      short8v wh0 = *(const short8v*)(wfhi + tb * 8);
      short8v wh1 = *(const short8v*)(wfhi + (tb + 64) * 8);
      short8v wl0 = *(const short8v*)(wflo + tb * 8);
      short8v wl1 = *(const short8v*)(wflo + (tb + 64) * 8);
      const int bo = l15 * BST + ks * 32 + g4 * 8;
      short8v bh0 = *(const short8v*)&Bhi[bo];
      short8v bh1 = *(const short8v*)&Bhi[bo + 16 * BST];
      short8v bl0 = *(const short8v*)&Blo[bo];
      short8v bl1 = *(const short8v*)&Blo[bo + 16 * BST];
      acc00 = MFMA16(wh0, bh0, acc00);
      acc00 = MFMA16(wl0, bh0, acc00);
      acc00 = MFMA16(wh0, bl0, acc00);
      acc01 = MFMA16(wh0, bh1, acc01);
      acc01 = MFMA16(wl0, bh1, acc01);
      acc01 = MFMA16(wh0, bl1, acc01);
      acc10 = MFMA16(wh1, bh0, acc10);
      acc10 = MFMA16(wl1, bh0, acc10);
      acc10 = MFMA16(wh1, bl0, acc10);
      acc11 = MFMA16(wh1, bh1, acc11);
      acc11 = MFMA16(wl1, bh1, acc11);
      acc11 = MFMA16(wh1, bl1, acc11);
    }
    __syncthreads();
    float mx0[4] = {0.f, 0.f, 0.f, 0.f};
    float mx1[4] = {0.f, 0.f, 0.f, 0.f};
    auto ep = [&](const f32x4& a, int mt_i, int nt, float* mxr) {
      const int co0 = (mt0 + mt_i) * 16 + g4 * 4;
      const int kp = nt * 16 + l15;
      const bool valid = kp < KK;
      f32x4 scv = *(const f32x4*)(bnsb + L * 256 + co0);
      f32x4 biv = *(const f32x4*)(bnsb + L * 256 + 128 + co0);
      float y[4];
#pragma unroll
      for (int r = 0; r < 4; r++) y[r] = fmaf(a[r], scv[r], biv[r]);
      if (addres && valid) {
        f32x4 xr = *(const f32x4*)&Xres[kp * XST + co0];
#pragma unroll
        for (int r = 0; r < 4; r++) y[r] += xr[r];
      }
#pragma unroll
      for (int r = 0; r < 4; r++) y[r] = fmaxf(y[r], 0.f);
      if (wres && valid) {
        f32x4 o = {y[0], y[1], y[2], y[3]};
        *(f32x4*)&Xres[kp * XST + co0] = o;
      }
      if (!pool) {
        if (valid) {
          unsigned b0 = __float_as_uint(y[0]), b1 = __float_as_uint(y[1]);
          unsigned b2 = __float_as_uint(y[2]), b3 = __float_as_uint(y[3]);
          unsigned h01 = (b0 >> 16) | (b1 & 0xFFFF0000u);
          unsigned h23 = (b2 >> 16) | (b3 & 0xFFFF0000u);
          *(uint2*)&Bhi[kp * BST + co0] = make_uint2(h01, h23);
          float r0 = __fsub_rn(y[0], __uint_as_float(b0 & 0xFFFF0000u));
          float r1 = __fsub_rn(y[1], __uint_as_float(b1 & 0xFFFF0000u));
          float r2 = __fsub_rn(y[2], __uint_as_float(b2 & 0xFFFF0000u));
          float r3 = __fsub_rn(y[3], __uint_as_float(b3 & 0xFFFF0000u));
          unsigned l01 = (__float_as_uint(r0) >> 16) | (__float_as_uint(r1) & 0xFFFF0000u);
          unsigned l23 = (__float_as_uint(r2) >> 16) | (__float_as_uint(r3) & 0xFFFF0000u);
          *(uint2*)&Blo[kp * BST + co0] = make_uint2(l01, l23);
        }
      } else {
#pragma unroll
        for (int r = 0; r < 4; r++) {
          float v = valid ? y[r] : 0.f;
          mxr[r] = fmaxf(mxr[r], v);
        }
      }
    };
    ep(acc00, 0, 0, mx0);
    ep(acc01, 0, 1, mx0);
    ep(acc10, 1, 0, mx1);
    ep(acc11, 1, 1, mx1);
    if (!pool) {
      __syncthreads();
    } else {
#pragma unroll
      for (int dstep = 1; dstep < 16; dstep <<= 1) {
#pragma unroll
        for (int r = 0; r < 4; r++) {
          mx0[r] = fmaxf(mx0[r], __shfl_xor(mx0[r], dstep));
          mx1[r] = fmaxf(mx1[r], __shfl_xor(mx1[r], dstep));
        }
      }
      if (l15 == 0) {
        f32x4 o0 = {mx0[0], mx0[1], mx0[2], mx0[3]};
        f32x4 o1 = {mx1[0], mx1[1], mx1[2], mx1[3]};
        *(f32x4*)&pre_out[q * 128 + mt0 * 16 + g4 * 4] = o0;
        *(f32x4*)&pre_out[q * 128 + (mt0 + 1) * 16 + g4 * 4] = o1;
      }
    }
  }
}

// ---------------------------------------------------------------------------
// PosExtraction (unchanged)
// ---------------------------------------------------------------------------
__global__ __launch_bounds__(256, 2) void k_pos(
    const float* __restrict__ pre_out, const float* __restrict__ wt_sq,
    const float* __restrict__ bnsb, float* __restrict__ out) {
  __shared__ float X[128][68];
  __shared__ float Y[128][68];
  const int blk = blockIdx.x, t = threadIdx.x;
  const int b = blk >> 4, s0 = (blk & 15) << 6;
  for (int e = t; e < 128 * 64; e += 256) {
    int sl = e >> 7, c = e & 127;
    X[c][sl] = pre_out[(b * SS + s0 + sl) * 128 + c];
  }
  __syncthreads();
  const int co0 = (t >> 3) << 2, p0 = (t & 7) << 3;
  float acc[4][8];
  auto conv = [&](const float (*IN)[68], const float* wt) {
#pragma unroll
    for (int i = 0; i < 4; i++)
#pragma unroll
      for (int j = 0; j < 8; j++) acc[i][j] = 0.f;
#pragma unroll 2
    for (int ci = 0; ci < 128; ci++) {
      float4 w = *(const float4*)(wt + ci * 128 + co0);
      float4 r0 = *(const float4*)&IN[ci][p0];
      float4 r1 = *(const float4*)&IN[ci][p0 + 4];
      float a[8] = {r0.x, r0.y, r0.z, r0.w, r1.x, r1.y, r1.z, r1.w};
#pragma unroll
      for (int j = 0; j < 8; j++) {
        acc[0][j] = fmaf(w.x, a[j], acc[0][j]);
        acc[1][j] = fmaf(w.y, a[j], acc[1][j]);
        acc[2][j] = fmaf(w.z, a[j], acc[2][j]);
        acc[3][j] = fmaf(w.w, a[j], acc[3][j]);
      }
    }
  };
  conv(X, wt_sq + 4 * 16384);
  {
    const float* bn = bnsb + 5 * 256;
#pragma unroll
    for (int i = 0; i < 4; i++) {
      float sc = bn[co0 + i], bi = bn[128 + co0 + i];
#pragma unroll
      for (int j = 0; j < 8; j++)
        Y[co0 + i][p0 + j] = fmaxf(fmaf(acc[i][j], sc, bi), 0.f);
    }
  }
  __syncthreads();
  conv(Y, wt_sq + 5 * 16384);
  {
    const float* bn = bnsb + 6 * 256;
#pragma unroll
    for (int i = 0; i < 4; i++) {
      float sc = bn[co0 + i], bi = bn[128 + co0 + i];
#pragma unroll
      for (int j = 0; j < 8; j++)
        X[co0 + i][p0 + j] =
            fmaxf(fmaf(acc[i][j], sc, bi) + X[co0 + i][p0 + j], 0.f);
    }
  }
  __syncthreads();
  conv(X, wt_sq + 6 * 16384);
  {
    const float* bn = bnsb + 7 * 256;
#pragma unroll
    for (int i = 0; i < 4; i++) {
      float sc = bn[co0 + i], bi = bn[128 + co0 + i];
#pragma unroll
      for (int j = 0; j < 8; j++)
        Y[co0 + i][p0 + j] = fmaxf(fmaf(acc[i][j], sc, bi), 0.f);
    }
  }
  __syncthreads();
  conv(Y, wt_sq + 7 * 16384);
  {
    const float* bn = bnsb + 8 * 256;
#pragma unroll
    for (int i = 0; i < 4; i++) {
      float sc = bn[co0 + i], bi = bn[128 + co0 + i];
      float4 o0, o1;
      float v;
      v = fmaxf(fmaf(acc[i][0], sc, bi) + X[co0 + i][p0 + 0], 0.f); o0.x = v;
      v = fmaxf(fmaf(acc[i][1], sc, bi) + X[co0 + i][p0 + 1], 0.f); o0.y = v;
      v = fmaxf(fmaf(acc[i][2], sc, bi) + X[co0 + i][p0 + 2], 0.f); o0.z = v;
      v = fmaxf(fmaf(acc[i][3], sc, bi) + X[co0 + i][p0 + 3], 0.f); o0.w = v;
      v = fmaxf(fmaf(acc[i][4], sc, bi) + X[co0 + i][p0 + 4], 0.f); o1.x = v;
      v = fmaxf(fmaf(acc[i][5], sc, bi) + X[co0 + i][p0 + 5], 0.f); o1.y = v;
      v = fmaxf(fmaf(acc[i][6], sc, bi) + X[co0 + i][p0 + 6], 0.f); o1.z = v;
      v = fmaxf(fmaf(acc[i][7], sc, bi) + X[co0 + i][p0 + 7], 0.f); o1.w = v;
      float* op = &out[(size_t)(b * 128 + co0 + i) * SS + s0 + p0];
      *(float4*)op = o0;
      *(float4*)(op + 4) = o1;
    }
  }
}

// ---------------------------------------------------------------------------
extern "C" void kernel_launch(void* const* d_in, const int* in_sizes, int n_in,
                              void* d_out, int out_size, void* d_ws, size_t ws_size,
                              hipStream_t stream) {
  (void)in_sizes; (void)n_in; (void)out_size; (void)ws_size;
  const float* xyz    = (const float*)d_in[0];
  const float* points = (const float*)d_in[1];
  const float* alpha  = (const float*)d_in[2];
  const float* beta   = (const float*)d_in[3];
  const float* tw     = (const float*)d_in[4];
  const float* tb     = (const float*)d_in[5];
  const float* tbn    = (const float*)d_in[6];
  const float* pw1    = (const float*)d_in[7];
  const float* pb1    = (const float*)d_in[8];
  const float* pbn1   = (const float*)d_in[9];
  const float* pw2    = (const float*)d_in[10];
  const float* pb2    = (const float*)d_in[11];
  const float* pbn2   = (const float*)d_in[12];
  const float* qw1    = (const float*)d_in[13];
  const float* qb1    = (const float*)d_in[14];
  const float* qbn1   = (const float*)d_in[15];
  const float* qw2    = (const float*)d_in[16];
  const float* qb2    = (const float*)d_in[17];
  const float* qbn2   = (const float*)d_in[18];

  char* ws = (char*)d_ws;
  size_t off = 0;
  auto alloc = [&](size_t bytes) -> char* {
    char* p = ws + off;
    off += (bytes + 255) & ~(size_t)255;
    return p;
  };
  float*  xs    = (float*)alloc(BB * NN * 4);
  float*  ys    = (float*)alloc(BB * NN * 4);
  float*  zs    = (float*)alloc(BB * NN * 4);
  float*  sb    = (float*)alloc(BB * NN * 4);
  float*  wt_sq = (float*)alloc(8 * 16384 * 4);
  float*  bnsb  = (float*)alloc(9 * 256 * 4);
  unsigned short* wfhi = (unsigned short*)alloc(168 * 512 * 2);
  unsigned short* wflo = (unsigned short*)alloc(168 * 512 * 2);
  float*  nxyz  = (float*)alloc(BB * SS * 3 * 4);
  float*  sa    = (float*)alloc(BB * SS * 4);
  float*  newp  = (float*)alloc(BB * SS * CC * 4);
  int*    knn   = (int*)alloc(BB * SS * KK * 4);
  double* spart = (double*)alloc(BB * SS * 2 * 8);
  float*  stdp  = (float*)alloc(256);
  float*  preo  = (float*)alloc((size_t)BB * SS * 128 * 4);
  float*  out   = (float*)d_out;

  const int prep_n = 8 * 128 * 128 + 9 * 128 + 168 * 64;
  hipLaunchKernelGGL(k_prep_xyz, dim3((BB * NN + 255) / 256), dim3(256), 0, stream,
                     xyz, xs, ys, zs, sb);
  hipLaunchKernelGGL(k_prep_w, dim3((prep_n + 255) / 256), dim3(256), 0, stream,
                     tw, pw1, pw2, qw1, qw2, tb, tbn, pb1, pbn1, pb2, pbn2,
                     qb1, qbn1, qb2, qbn2, wt_sq, bnsb, wfhi, wflo);
  hipLaunchKernelGGL(k_fps, dim3(BB), dim3(64), 0, stream,
                     xs, ys, zs, sb, points, nxyz, sa, newp);
  hipLaunchKernelGGL(k_knn, dim3(BB * SS / 4), dim3(256), 0, stream,
                     xs, ys, zs, nxyz, sa, points, newp, knn, spart);
  hipLaunchKernelGGL(k_stdfin, dim3(BB), dim3(256), 0, stream, spart, stdp);
  hipLaunchKernelGGL(k_pre, dim3(BB * SS), dim3(256), 0, stream,
                     points, alpha, beta, xs, ys, zs, nxyz, newp, stdp, knn,
                     wfhi, wflo, bnsb, preo);
  hipLaunchKernelGGL(k_pos, dim3(BB * SS / 64), dim3(256), 0, stream,
                     preo, wt_sq, bnsb, out);
}

// Round 16
// 1035.609 us; speedup vs baseline: 1.9683x; 1.9683x over previous
//
#include <hip/hip_runtime.h>
#include <hip/hip_bf16.h>
#include <stdint.h>
#include <math.h>

#define DEVINL static __device__ __forceinline__

static constexpr int BB = 8, NN = 4096, SS = 1024, KK = 24, CC = 64;
static constexpr int INCH = 131, OUTCH = 128;

typedef __attribute__((ext_vector_type(8))) short short8v;  // 8 bf16 (4 VGPR)
typedef __attribute__((ext_vector_type(4))) float f32x4;
typedef __attribute__((ext_vector_type(2))) float f32x2;

#define MFMA16(a, b, c) __builtin_amdgcn_mfma_f32_16x16x32_bf16(a, b, c, 0, 0, 0)

// Truncation-based compensated bf16 split: hi = trunc(v); lo compensates
// exactly (v - trunc(v) is exact in f32).
DEVINL unsigned short bfhi(float v) {
  return (unsigned short)(__float_as_uint(v) >> 16);
}
DEVINL float bfhif(float v) {
  return __uint_as_float(__float_as_uint(v) & 0xFFFF0000u);
}
DEVINL unsigned short bflo(float v) {
  float r = __fsub_rn(v, bfhif(v));
  return (unsigned short)(__float_as_uint(r) >> 16);
}

// ---------------------------------------------------------------------------
// prep 1: xyz -> SoA f32 + per-point ||p||^2 (exact np op order, no FMA fusion)
// ---------------------------------------------------------------------------
__global__ __launch_bounds__(256) void k_prep_xyz(
    const float* __restrict__ xyz,
    float* __restrict__ xs, float* __restrict__ ys,
    float* __restrict__ zs, float* __restrict__ sb) {
  int e = blockIdx.x * 256 + threadIdx.x;
  if (e >= BB * NN) return;
  float x = xyz[e * 3 + 0];
  float y = xyz[e * 3 + 1];
  float z = xyz[e * 3 + 2];
  xs[e] = x; ys[e] = y; zs[e] = z;
  sb[e] = __fadd_rn(__fadd_rn(__fmul_rn(x, x), __fmul_rn(y, y)), __fmul_rn(z, z));
}

// ---------------------------------------------------------------------------
// prep 2: (a) wt_sq transpose for k_pos, (b) folded BN scale/bias, (c) MFMA
// weight fragments for k_pre layers 0..4 in split-bf16 (trunc hi / comp lo).
// ---------------------------------------------------------------------------
__global__ __launch_bounds__(256) void k_prep_w(
    const float* __restrict__ tw,
    const float* __restrict__ pw1, const float* __restrict__ pw2,
    const float* __restrict__ qw1, const float* __restrict__ qw2,
    const float* __restrict__ tb,  const float* __restrict__ tbn,
    const float* __restrict__ pb1, const float* __restrict__ pbn1,
    const float* __restrict__ pb2, const float* __restrict__ pbn2,
    const float* __restrict__ qb1, const float* __restrict__ qbn1,
    const float* __restrict__ qb2, const float* __restrict__ qbn2,
    float* __restrict__ wt_sq, float* __restrict__ bnsb,
    unsigned short* __restrict__ wfhi, unsigned short* __restrict__ wflo) {
  int e = blockIdx.x * 256 + threadIdx.x;
  const int NSQ = 8 * 128 * 128;  // 131072 (k_pos still uses layers 4..7)
  const int NBN = 9 * 128;
  const int NFR = 168 * 64;       // fragment fill threads
  if (e < NSQ) {
    int layer = e >> 14, m = e & 16383;
    int ci = m >> 7, co = m & 127;
    const float* src;
    switch (layer) {
      case 0: src = pw1;         break;
      case 1: src = pw2;         break;
      case 2: src = pw1 + 16384; break;
      case 3: src = pw2 + 16384; break;
      case 4: src = qw1;         break;
      case 5: src = qw2;         break;
      case 6: src = qw1 + 16384; break;
      default: src = qw2 + 16384; break;
    }
    wt_sq[layer * 16384 + ci * 128 + co] = src[co * 128 + ci];
  } else if (e < NSQ + NBN) {
    int r = e - NSQ;
    int L = r >> 7, co = r & 127;
    const float *bn, *bc;
    switch (L) {
      case 0: bn = tbn;        bc = tb;        break;
      case 1: bn = pbn1;       bc = pb1;       break;
      case 2: bn = pbn2;       bc = pb2;       break;
      case 3: bn = pbn1 + 512; bc = pb1 + 128; break;
      case 4: bn = pbn2 + 512; bc = pb2 + 128; break;
      case 5: bn = qbn1;       bc = qb1;       break;
      case 6: bn = qbn2;       bc = qb2;       break;
      case 7: bn = qbn1 + 512; bc = qb1 + 128; break;
      default: bn = qbn2 + 512; bc = qb2 + 128; break;
    }
    float g  = bn[co];
    float be = bn[128 + co];
    float mu = bn[256 + co];
    float va = bn[384 + co];
    float bcv = bc[co];
    float sc = g / sqrtf(va + 1e-5f);
    float bi = (bcv - mu) * sc + be;
    bnsb[L * 256 + co] = sc;
    bnsb[L * 256 + 128 + co] = bi;
  } else if (e < NSQ + NBN + NFR) {
    int r = e - (NSQ + NBN);
    int T = r >> 6, lane = r & 63;
    int L, ks, mt;
    if (T < 40) { L = 0; ks = T >> 3; mt = T & 7; }
    else { int r2 = T - 40; L = 1 + (r2 >> 5); int r3 = r2 & 31; ks = r3 >> 3; mt = r3 & 7; }
    const float* src;
    int K, stride;
    switch (L) {
      case 0:  src = tw;          K = 131; stride = 131; break;
      case 1:  src = pw1;         K = 128; stride = 128; break;
      case 2:  src = pw2;         K = 128; stride = 128; break;
      case 3:  src = pw1 + 16384; K = 128; stride = 128; break;
      default: src = pw2 + 16384; K = 128; stride = 128; break;
    }
    int m = lane & 15, kb = lane >> 4;
    int co = mt * 16 + m;
    int base = (T * 64 + lane) * 8;
#pragma unroll
    for (int j = 0; j < 8; j++) {
      int ci = ks * 32 + kb * 8 + j;
      float w = (ci < K) ? src[co * stride + ci] : 0.f;
      wfhi[base + j] = bfhi(w);
      wflo[base + j] = bflo(w);
    }
  }
}

// ---------------------------------------------------------------------------
// DPP wave max (ALU-only). row_shr:1/2/4/8 + row_bcast:15/31 leave the
// full-wave result in lane 63. Invalid lanes read `old` = identity (-inf).
// ---------------------------------------------------------------------------
DEVINL float wave_max_f32_l63(float x) {
#define STEPF(C)                                                                \
  {                                                                             \
    int o = __builtin_amdgcn_update_dpp(0xff800000, __float_as_int(x), C, 0xf, 0xf, false); \
    x = fmaxf(x, __int_as_float(o));                                            \
  }
  STEPF(0x111) STEPF(0x112) STEPF(0x114) STEPF(0x118) STEPF(0x142) STEPF(0x143)
#undef STEPF
  return x;
}

// ---------------------------------------------------------------------------
// FPS v8 (best measured, 635 us): one block (256 thr = 4 waves, 1 wave/SIMD)
// per batch; 16 contiguous points/thread as 8 packed f32x2 pairs. Packed-FP32
// distance update with scoped fp-contract(off) (exact np op order). Inline
// (val,n) select; DPP f32-max -> readlane -> ballot -> ffs -> readlane;
// 1 u64 key/wave in LDS, one barrier, 2-level tree; coords via lxl[n].
// ---------------------------------------------------------------------------
__global__ __launch_bounds__(256, 1) void k_fps(
    const float* __restrict__ xs, const float* __restrict__ ys,
    const float* __restrict__ zs, const float* __restrict__ sb,
    const float* __restrict__ points,
    float* __restrict__ nxyz, float* __restrict__ sa, float* __restrict__ newp) {
  __shared__ float lxl[NN], lyl[NN], lzl[NN];
  __shared__ unsigned long long pk[2][4];
  __shared__ int fpsl[SS];
  const int b = blockIdx.x, t = threadIdx.x;
  const int wid = t >> 6, lane = t & 63;
  const float* bx = xs + b * NN;
  const float* by = ys + b * NN;
  const float* bz = zs + b * NN;
  f32x2 rx[8], ry[8], rz[8], d[8];
  const int n0 = t * 16;
#pragma unroll
  for (int j = 0; j < 8; j++) {
    int n = n0 + 2 * j;
    rx[j].x = bx[n]; rx[j].y = bx[n + 1];
    ry[j].x = by[n]; ry[j].y = by[n + 1];
    rz[j].x = bz[n]; rz[j].y = bz[n + 1];
    lxl[n] = rx[j].x; lxl[n + 1] = rx[j].y;
    lyl[n] = ry[j].x; lyl[n + 1] = ry[j].y;
    lzl[n] = rz[j].x; lzl[n + 1] = rz[j].y;
    d[j].x = 1e10f; d[j].y = 1e10f;
  }
  __syncthreads();
  float px = lxl[0], py = lyl[0], pz = lzl[0];
  if (t == 0) fpsl[0] = 0;
#pragma unroll 1
  for (int i = 1; i < SS; i++) {
    float bestval = -1.f;
    int bestn = 0;
    f32x2 px2, py2, pz2;
    px2.x = px; px2.y = px;
    py2.x = py; py2.y = py;
    pz2.x = pz; pz2.y = pz;
#pragma unroll
    for (int j = 0; j < 8; j++) {
      f32x2 dd;
      {
#pragma clang fp contract(off)
        f32x2 dx = rx[j] - px2;
        f32x2 dy = ry[j] - py2;
        f32x2 dz = rz[j] - pz2;
        dd = (dx * dx + dy * dy) + dz * dz;
      }
      float nd0 = fminf(d[j].x, dd.x);
      float nd1 = fminf(d[j].y, dd.y);
      d[j].x = nd0; d[j].y = nd1;
      if (nd0 > bestval) { bestval = nd0; bestn = n0 + 2 * j; }      // first-n
      if (nd1 > bestval) { bestval = nd1; bestn = n0 + 2 * j + 1; }  // on tie
    }
    float wmax = __int_as_float(
        __builtin_amdgcn_readlane(__float_as_int(wave_max_f32_l63(bestval)), 63));
    unsigned long long el = __ballot(bestval == wmax);
    int fl = (int)__ffsll(el) - 1;            // lowest eligible lane = min n
    int wn = __builtin_amdgcn_readlane(bestn, fl);
    if (lane == 0)
      pk[i & 1][wid] = ((unsigned long long)__float_as_uint(wmax) << 32) |
                       (unsigned)(NN - 1 - wn);
    __syncthreads();
    const unsigned long long* P = pk[i & 1];
    unsigned long long k0 = P[0], k1 = P[1], k2 = P[2], k3 = P[3];
    unsigned long long m01 = k1 > k0 ? k1 : k0;
    unsigned long long m23 = k3 > k2 ? k3 : k2;
    unsigned long long g = m23 > m01 ? m23 : m01;
    int n = NN - 1 - (int)(unsigned)g;
    px = lxl[n]; py = lyl[n]; pz = lzl[n];
    if (t == 0) fpsl[i] = n;
  }
  __syncthreads();
  for (int s = t; s < SS; s += 256) {
    int row = fpsl[s];
    nxyz[(b * SS + s) * 3 + 0] = lxl[row];
    nxyz[(b * SS + s) * 3 + 1] = lyl[row];
    nxyz[(b * SS + s) * 3 + 2] = lzl[row];
    sa[b * SS + s] = sb[b * NN + row];
  }
  for (int e = t; e < SS * CC; e += 256) {
    int s = e >> 6, c = e & 63;
    int row = fpsl[s];
    newp[(b * SS + s) * CC + c] = points[(b * NN + row) * CC + c];
  }
}

// ---------------------------------------------------------------------------
// KNN + std partial sums (u64-shuffle extraction; best measured config)
// ---------------------------------------------------------------------------
__global__ __launch_bounds__(256, 2) void k_knn(
    const float* __restrict__ xs, const float* __restrict__ ys,
    const float* __restrict__ zs,
    const float* __restrict__ nxyz, const float* __restrict__ sa,
    const float* __restrict__ points, const float* __restrict__ newp,
    int* __restrict__ knn, double* __restrict__ spart) {
  __shared__ float lx[NN], ly[NN], lz[NN];
  __shared__ int selk[4][KK];
  const int blk = blockIdx.x, t = threadIdx.x, wid = t >> 6, lane = t & 63;
  const int b = blk >> 8;
  for (int e = t; e < NN; e += 256) {
    lx[e] = xs[b * NN + e]; ly[e] = ys[b * NN + e]; lz[e] = zs[b * NN + e];
  }
  __syncthreads();
  const int q = blk * 4 + wid;
  float qx = nxyz[q * 3 + 0], qy = nxyz[q * 3 + 1], qz = nxyz[q * 3 + 2];
  float qa = sa[q];
  unsigned keys[64];
#pragma unroll
  for (int j = 0; j < 64; j++) {
    int n = j * 64 + lane;
    float x = lx[n], y = ly[n], z = lz[n];
    float sbn = __fadd_rn(__fadd_rn(__fmul_rn(x, x), __fmul_rn(y, y)), __fmul_rn(z, z));
    float dot = __fadd_rn(__fadd_rn(__fmul_rn(qx, x), __fmul_rn(qy, y)), __fmul_rn(qz, z));
    float dd = __fsub_rn(__fadd_rn(qa, sbn), __fmul_rn(2.0f, dot));
    unsigned u = __float_as_uint(dd);
    u ^= (0x80000000u | (unsigned)((int)u >> 31));
    keys[j] = u;
  }
#pragma unroll 1
  for (int r = 0; r < KK; r++) {
    unsigned bv = keys[0];
    int bj = 0;
#pragma unroll
    for (int j = 1; j < 64; j++) {
      if (keys[j] < bv) { bv = keys[j]; bj = j; }
    }
    unsigned long long gk = ((unsigned long long)bv << 32) | (unsigned)(bj * 64 + lane);
#pragma unroll
    for (int m = 1; m < 64; m <<= 1) {
      unsigned long long o = __shfl_xor(gk, m);
      gk = o < gk ? o : gk;
    }
    int n = (int)(unsigned)gk;
    if (lane == 0) { knn[q * KK + r] = n; selk[wid][r] = n; }
    if (lane == (n & 63)) {
      int jj = n >> 6;
#pragma unroll
      for (int j = 0; j < 64; j++)
        if (j == jj) keys[j] = 0xFFFFFFFFu;
    }
  }
  double s1 = 0.0, s2 = 0.0;
#pragma unroll 1
  for (int i = 0; i < 26; i++) {
    int e = lane + 64 * i;
    if (e < KK * 67) {
      int k = e / 67, c = e - k * 67;
      int n = selk[wid][k];
      float g, mm;
      if (c < CC) {
        g = points[(b * NN + n) * CC + c];
        mm = newp[q * CC + c];
      } else {
        int cc = c - CC;
        g = cc == 0 ? lx[n] : (cc == 1 ? ly[n] : lz[n]);
        mm = nxyz[q * 3 + cc];
      }
      float v = __fsub_rn(g, mm);
      s1 += (double)v;
      s2 += (double)v * (double)v;
    }
  }
#pragma unroll
  for (int m = 1; m < 64; m <<= 1) {
    s1 += __shfl_xor(s1, m);
    s2 += __shfl_xor(s2, m);
  }
  if (lane == 0) { spart[q * 2 + 0] = s1; spart[q * 2 + 1] = s2; }
}

// ---------------------------------------------------------------------------
// finalize std per batch -> stdp = std + 1e-5
// ---------------------------------------------------------------------------
__global__ __launch_bounds__(256) void k_stdfin(
    const double* __restrict__ spart, float* __restrict__ stdp) {
  __shared__ double a1[256], a2[256];
  const int b = blockIdx.x, t = threadIdx.x;
  double s1 = 0.0, s2 = 0.0;
  for (int i = t; i < SS; i += 256) {
    s1 += spart[(b * SS + i) * 2 + 0];
    s2 += spart[(b * SS + i) * 2 + 1];
  }
  a1[t] = s1; a2[t] = s2;
  __syncthreads();
  for (int w = 128; w > 0; w >>= 1) {
    if (t < w) { a1[t] += a1[t + w]; a2[t] += a2[t + w]; }
    __syncthreads();
  }
  if (t == 0) {
    const double n = (double)SS * KK * 67;
    double m = a1[0] / n;
    double var = (a2[0] - a1[0] * m) / (n - 1.0);
    if (var < 0.0) var = 0.0;
    float stdf = (float)sqrt(var);
    stdp[b] = stdf + 1e-5f;
  }
}

// ---------------------------------------------------------------------------
// fused PreExtraction v5 (round-11 best config): MFMA split-bf16 3-pass,
// truncation split, fully unrolled, LB(256,4).
// ---------------------------------------------------------------------------
static constexpr int BST = 168;  // acts row stride (bf16 elems)
static constexpr int XST = 132;  // residual row stride (f32)

__global__ __launch_bounds__(256, 4) void k_pre(
    const float* __restrict__ points,
    const float* __restrict__ alpha, const float* __restrict__ beta,
    const float* __restrict__ xs, const float* __restrict__ ys, const float* __restrict__ zs,
    const float* __restrict__ nxyz, const float* __restrict__ newp,
    const float* __restrict__ stdp, const int* __restrict__ knn,
    const unsigned short* __restrict__ wfhi, const unsigned short* __restrict__ wflo,
    const float* __restrict__ bnsb, float* __restrict__ pre_out) {
  __shared__ unsigned short Bhi[32 * BST];
  __shared__ unsigned short Blo[32 * BST];
  __shared__ float Xres[32 * XST];
  __shared__ int kn[KK];
  __shared__ float npl[CC], nxl[3], al[67], bt[67];
  __shared__ float stds;
  const int q = blockIdx.x, b = q >> 10, t = threadIdx.x;
  for (int e = t; e < 32 * BST; e += 256) { Bhi[e] = 0; Blo[e] = 0; }
  if (t < KK) kn[t] = knn[q * KK + t];
  if (t < 67) { al[t] = alpha[t]; bt[t] = beta[t]; }
  if (t < CC) npl[t] = newp[q * CC + t];
  if (t < 3) nxl[t] = nxyz[q * 3 + t];
  if (t == 0) stds = stdp[b];
  __syncthreads();
  for (int e = t; e < KK * 67; e += 256) {
    int k = e / 67, c = e - k * 67;
    int n = kn[k];
    float g, mm;
    if (c < CC) {
      g = points[(b * NN + n) * CC + c];
      mm = npl[c];
    } else {
      int cc = c - CC;
      g = cc == 0 ? xs[b * NN + n] : (cc == 1 ? ys[b * NN + n] : zs[b * NN + n]);
      mm = nxl[cc];
    }
    float v = __fsub_rn(g, mm);
    float tt = __fdiv_rn(v, stds);
    float val = __fadd_rn(__fmul_rn(al[c], tt), bt[c]);
    Bhi[k * BST + c] = bfhi(val);
    Blo[k * BST + c] = bflo(val);
  }
  for (int e = t; e < CC * KK; e += 256) {
    int c = e / KK, k = e - c * KK;
    float val = npl[c];
    Bhi[k * BST + 67 + c] = bfhi(val);
    Blo[k * BST + 67 + c] = bflo(val);
  }
  __syncthreads();

  const int wv = t >> 6, lane = t & 63;
  const int g4 = lane >> 4;
  const int l15 = lane & 15;
  const int mt0 = wv * 2;

#pragma unroll
  for (int L = 0; L < 5; ++L) {
    const int nks = (L == 0) ? 5 : 4;
    const int wtb = (L == 0) ? 0 : (8 + 32 * L);
    const bool addres = (L == 2) || (L == 4);
    const bool wres = (L == 0) || (L == 2);
    const bool pool = (L == 4);
    f32x4 acc00 = {0.f, 0.f, 0.f, 0.f}, acc01 = {0.f, 0.f, 0.f, 0.f};
    f32x4 acc10 = {0.f, 0.f, 0.f, 0.f}, acc11 = {0.f, 0.f, 0.f, 0.f};
#pragma unroll
    for (int ks = 0; ks < nks; ++ks) {
      const int tb = (wtb + ks * 8 + mt0) * 64 + lane;
      short8v wh0 = *(const short8v*)(wfhi + tb * 8);
      short8v wh1 = *(const short8v*)(wfhi + (tb + 64) * 8);
      short8v wl0 = *(const short8v*)(wflo + tb * 8);
      short8v wl1 = *(const short8v*)(wflo + (tb + 64) * 8);
      const int bo = l15 * BST + ks * 32 + g4 * 8;
      short8v bh0 = *(const short8v*)&Bhi[bo];
      short8v bh1 = *(const short8v*)&Bhi[bo + 16 * BST];
      short8v bl0 = *(const short8v*)&Blo[bo];
      short8v bl1 = *(const short8v*)&Blo[bo + 16 * BST];
      acc00 = MFMA16(wh0, bh0, acc00);
      acc00 = MFMA16(wl0, bh0, acc00);
      acc00 = MFMA16(wh0, bl0, acc00);
      acc01 = MFMA16(wh0, bh1, acc01);
      acc01 = MFMA16(wl0, bh1, acc01);
      acc01 = MFMA16(wh0, bl1, acc01);
      acc10 = MFMA16(wh1, bh0, acc10);
      acc10 = MFMA16(wl1, bh0, acc10);
      acc10 = MFMA16(wh1, bl0, acc10);
      acc11 = MFMA16(wh1, bh1, acc11);
      acc11 = MFMA16(wl1, bh1, acc11);
      acc11 = MFMA16(wh1, bl1, acc11);
    }
    __syncthreads();
    float mx0[4] = {0.f, 0.f, 0.f, 0.f};
    float mx1[4] = {0.f, 0.f, 0.f, 0.f};
    auto ep = [&](const f32x4& a, int mt_i, int nt, float* mxr) {
      const int co0 = (mt0 + mt_i) * 16 + g4 * 4;
      const int kp = nt * 16 + l15;
      const bool valid = kp < KK;
      f32x4 scv = *(const f32x4*)(bnsb + L * 256 + co0);
      f32x4 biv = *(const f32x4*)(bnsb + L * 256 + 128 + co0);
      float y[4];
#pragma unroll
      for (int r = 0; r < 4; r++) y[r] = fmaf(a[r], scv[r], biv[r]);
      if (addres && valid) {
        f32x4 xr = *(const f32x4*)&Xres[kp * XST + co0];
#pragma unroll
        for (int r = 0; r < 4; r++) y[r] += xr[r];
      }
#pragma unroll
      for (int r = 0; r < 4; r++) y[r] = fmaxf(y[r], 0.f);
      if (wres && valid) {
        f32x4 o = {y[0], y[1], y[2], y[3]};
        *(f32x4*)&Xres[kp * XST + co0] = o;
      }
      if (!pool) {
        if (valid) {
          unsigned b0 = __float_as_uint(y[0]), b1 = __float_as_uint(y[1]);
          unsigned b2 = __float_as_uint(y[2]), b3 = __float_as_uint(y[3]);
          unsigned h01 = (b0 >> 16) | (b1 & 0xFFFF0000u);
          unsigned h23 = (b2 >> 16) | (b3 & 0xFFFF0000u);
          *(uint2*)&Bhi[kp * BST + co0] = make_uint2(h01, h23);
          float r0 = __fsub_rn(y[0], __uint_as_float(b0 & 0xFFFF0000u));
          float r1 = __fsub_rn(y[1], __uint_as_float(b1 & 0xFFFF0000u));
          float r2 = __fsub_rn(y[2], __uint_as_float(b2 & 0xFFFF0000u));
          float r3 = __fsub_rn(y[3], __uint_as_float(b3 & 0xFFFF0000u));
          unsigned l01 = (__float_as_uint(r0) >> 16) | (__float_as_uint(r1) & 0xFFFF0000u);
          unsigned l23 = (__float_as_uint(r2) >> 16) | (__float_as_uint(r3) & 0xFFFF0000u);
          *(uint2*)&Blo[kp * BST + co0] = make_uint2(l01, l23);
        }
      } else {
#pragma unroll
        for (int r = 0; r < 4; r++) {
          float v = valid ? y[r] : 0.f;
          mxr[r] = fmaxf(mxr[r], v);
        }
      }
    };
    ep(acc00, 0, 0, mx0);
    ep(acc01, 0, 1, mx0);
    ep(acc10, 1, 0, mx1);
    ep(acc11, 1, 1, mx1);
    if (!pool) {
      __syncthreads();
    } else {
#pragma unroll
      for (int dstep = 1; dstep < 16; dstep <<= 1) {
#pragma unroll
        for (int r = 0; r < 4; r++) {
          mx0[r] = fmaxf(mx0[r], __shfl_xor(mx0[r], dstep));
          mx1[r] = fmaxf(mx1[r], __shfl_xor(mx1[r], dstep));
        }
      }
      if (l15 == 0) {
        f32x4 o0 = {mx0[0], mx0[1], mx0[2], mx0[3]};
        f32x4 o1 = {mx1[0], mx1[1], mx1[2], mx1[3]};
        *(f32x4*)&pre_out[q * 128 + mt0 * 16 + g4 * 4] = o0;
        *(f32x4*)&pre_out[q * 128 + (mt0 + 1) * 16 + g4 * 4] = o1;
      }
    }
  }
}

// ---------------------------------------------------------------------------
// PosExtraction (unchanged)
// ---------------------------------------------------------------------------
__global__ __launch_bounds__(256, 2) void k_pos(
    const float* __restrict__ pre_out, const float* __restrict__ wt_sq,
    const float* __restrict__ bnsb, float* __restrict__ out) {
  __shared__ float X[128][68];
  __shared__ float Y[128][68];
  const int blk = blockIdx.x, t = threadIdx.x;
  const int b = blk >> 4, s0 = (blk & 15) << 6;
  for (int e = t; e < 128 * 64; e += 256) {
    int sl = e >> 7, c = e & 127;
    X[c][sl] = pre_out[(b * SS + s0 + sl) * 128 + c];
  }
  __syncthreads();
  const int co0 = (t >> 3) << 2, p0 = (t & 7) << 3;
  float acc[4][8];
  auto conv = [&](const float (*IN)[68], const float* wt) {
#pragma unroll
    for (int i = 0; i < 4; i++)
#pragma unroll
      for (int j = 0; j < 8; j++) acc[i][j] = 0.f;
#pragma unroll 2
    for (int ci = 0; ci < 128; ci++) {
      float4 w = *(const float4*)(wt + ci * 128 + co0);
      float4 r0 = *(const float4*)&IN[ci][p0];
      float4 r1 = *(const float4*)&IN[ci][p0 + 4];
      float a[8] = {r0.x, r0.y, r0.z, r0.w, r1.x, r1.y, r1.z, r1.w};
#pragma unroll
      for (int j = 0; j < 8; j++) {
        acc[0][j] = fmaf(w.x, a[j], acc[0][j]);
        acc[1][j] = fmaf(w.y, a[j], acc[1][j]);
        acc[2][j] = fmaf(w.z, a[j], acc[2][j]);
        acc[3][j] = fmaf(w.w, a[j], acc[3][j]);
      }
    }
  };
  conv(X, wt_sq + 4 * 16384);
  {
    const float* bn = bnsb + 5 * 256;
#pragma unroll
    for (int i = 0; i < 4; i++) {
      float sc = bn[co0 + i], bi = bn[128 + co0 + i];
#pragma unroll
      for (int j = 0; j < 8; j++)
        Y[co0 + i][p0 + j] = fmaxf(fmaf(acc[i][j], sc, bi), 0.f);
    }
  }
  __syncthreads();
  conv(Y, wt_sq + 5 * 16384);
  {
    const float* bn = bnsb + 6 * 256;
#pragma unroll
    for (int i = 0; i < 4; i++) {
      float sc = bn[co0 + i], bi = bn[128 + co0 + i];
#pragma unroll
      for (int j = 0; j < 8; j++)
        X[co0 + i][p0 + j] =
            fmaxf(fmaf(acc[i][j], sc, bi) + X[co0 + i][p0 + j], 0.f);
    }
  }
  __syncthreads();
  conv(X, wt_sq + 6 * 16384);
  {
    const float* bn = bnsb + 7 * 256;
#pragma unroll
    for (int i = 0; i < 4; i++) {
      float sc = bn[co0 + i], bi = bn[128 + co0 + i];
#pragma unroll
      for (int j = 0; j < 8; j++)
        Y[co0 + i][p0 + j] = fmaxf(fmaf(acc[i][j], sc, bi), 0.f);
    }
  }
  __syncthreads();
  conv(Y, wt_sq + 7 * 16384);
  {
    const float* bn = bnsb + 8 * 256;
#pragma unroll
    for (int i = 0; i < 4; i++) {
      float sc = bn[co0 + i], bi = bn[128 + co0 + i];
      float4 o0, o1;
      float v;
      v = fmaxf(fmaf(acc[i][0], sc, bi) + X[co0 + i][p0 + 0], 0.f); o0.x = v;
      v = fmaxf(fmaf(acc[i][1], sc, bi) + X[co0 + i][p0 + 1], 0.f); o0.y = v;
      v = fmaxf(fmaf(acc[i][2], sc, bi) + X[co0 + i][p0 + 2], 0.f); o0.z = v;
      v = fmaxf(fmaf(acc[i][3], sc, bi) + X[co0 + i][p0 + 3], 0.f); o0.w = v;
      v = fmaxf(fmaf(acc[i][4], sc, bi) + X[co0 + i][p0 + 4], 0.f); o1.x = v;
      v = fmaxf(fmaf(acc[i][5], sc, bi) + X[co0 + i][p0 + 5], 0.f); o1.y = v;
      v = fmaxf(fmaf(acc[i][6], sc, bi) + X[co0 + i][p0 + 6], 0.f); o1.z = v;
      v = fmaxf(fmaf(acc[i][7], sc, bi) + X[co0 + i][p0 + 7], 0.f); o1.w = v;
      float* op = &out[(size_t)(b * 128 + co0 + i) * SS + s0 + p0];
      *(float4*)op = o0;
      *(float4*)(op + 4) = o1;
    }
  }
}

// ---------------------------------------------------------------------------
extern "C" void kernel_launch(void* const* d_in, const int* in_sizes, int n_in,
                              void* d_out, int out_size, void* d_ws, size_t ws_size,
                              hipStream_t stream) {
  (void)in_sizes; (void)n_in; (void)out_size; (void)ws_size;
  const float* xyz    = (const float*)d_in[0];
  const float* points = (const float*)d_in[1];
  const float* alpha  = (const float*)d_in[2];
  const float* beta   = (const float*)d_in[3];
  const float* tw     = (const float*)d_in[4];
  const float* tb     = (const float*)d_in[5];
  const float* tbn    = (const float*)d_in[6];
  const float* pw1    = (const float*)d_in[7];
  const float* pb1    = (const float*)d_in[8];
  const float* pbn1   = (const float*)d_in[9];
  const float* pw2    = (const float*)d_in[10];
  const float* pb2    = (const float*)d_in[11];
  const float* pbn2   = (const float*)d_in[12];
  const float* qw1    = (const float*)d_in[13];
  const float* qb1    = (const float*)d_in[14];
  const float* qbn1   = (const float*)d_in[15];
  const float* qw2    = (const float*)d_in[16];
  const float* qb2    = (const float*)d_in[17];
  const float* qbn2   = (const float*)d_in[18];

  char* ws = (char*)d_ws;
  size_t off = 0;
  auto alloc = [&](size_t bytes) -> char* {
    char* p = ws + off;
    off += (bytes + 255) & ~(size_t)255;
    return p;
  };
  float*  xs    = (float*)alloc(BB * NN * 4);
  float*  ys    = (float*)alloc(BB * NN * 4);
  float*  zs    = (float*)alloc(BB * NN * 4);
  float*  sb    = (float*)alloc(BB * NN * 4);
  float*  wt_sq = (float*)alloc(8 * 16384 * 4);
  float*  bnsb  = (float*)alloc(9 * 256 * 4);
  unsigned short* wfhi = (unsigned short*)alloc(168 * 512 * 2);
  unsigned short* wflo = (unsigned short*)alloc(168 * 512 * 2);
  float*  nxyz  = (float*)alloc(BB * SS * 3 * 4);
  float*  sa    = (float*)alloc(BB * SS * 4);
  float*  newp  = (float*)alloc(BB * SS * CC * 4);
  int*    knn   = (int*)alloc(BB * SS * KK * 4);
  double* spart = (double*)alloc(BB * SS * 2 * 8);
  float*  stdp  = (float*)alloc(256);
  float*  preo  = (float*)alloc((size_t)BB * SS * 128 * 4);
  float*  out   = (float*)d_out;

  const int prep_n = 8 * 128 * 128 + 9 * 128 + 168 * 64;
  hipLaunchKernelGGL(k_prep_xyz, dim3((BB * NN + 255) / 256), dim3(256), 0, stream,
                     xyz, xs, ys, zs, sb);
  hipLaunchKernelGGL(k_prep_w, dim3((prep_n + 255) / 256), dim3(256), 0, stream,
                     tw, pw1, pw2, qw1, qw2, tb, tbn, pb1, pbn1, pb2, pbn2,
                     qb1, qbn1, qb2, qbn2, wt_sq, bnsb, wfhi, wflo);
  hipLaunchKernelGGL(k_fps, dim3(BB), dim3(256), 0, stream,
                     xs, ys, zs, sb, points, nxyz, sa, newp);
  hipLaunchKernelGGL(k_knn, dim3(BB * SS / 4), dim3(256), 0, stream,
                     xs, ys, zs, nxyz, sa, points, newp, knn, spart);
  hipLaunchKernelGGL(k_stdfin, dim3(BB), dim3(256), 0, stream, spart, stdp);
  hipLaunchKernelGGL(k_pre, dim3(BB * SS), dim3(256), 0, stream,
                     points, alpha, beta, xs, ys, zs, nxyz, newp, stdp, knn,
                     wfhi, wflo, bnsb, preo);
  hipLaunchKernelGGL(k_pos, dim3(BB * SS / 64), dim3(256), 0, stream,
                     preo, wt_sq, bnsb, out);
}